// Round 11
// baseline (594.418 us; speedup 1.0000x reference)
//
#include <hip/hip_runtime.h>
#include <math.h>

// Problem constants (from reference): B=8, C=32, F=32, K=3, H=W=32
#define NB 8
#define NC 32
#define NF 32
#define NH 32
#define NW 32
#define NQ 9
#define CSPLIT 8            // channel chunks; block covers 4 channels
#define CPB (NC / CSPLIT)   // channels per block = 4
#define TS 34               // padded tile row stride (W+2)
#define TROWS 34            // full padded image rows (32 + 2 halo)
#define TILE_N (TROWS * TS) // 1156
#define CROWS (NQ * CPB)    // 36 coefficient rows per block
#define CROW_F 16           // floats per padded coeff row (a0..5,_,_,d0..3,_x4)

typedef float f2 __attribute__((ext_vector_type(2)));
__device__ __forceinline__ f2 sp(float v) { return (f2){v, v}; }

// v9: LDS-coefficient feed AT FULL OCCUPANCY (the untested quadrant).
// Evidence: v7 measured ~124 issued instr per (q,c) iter vs ~45 ideal ->
// VALU-issue-bound with ~2.5x mov/wait fat (SGPR->VGPR splat movs from
// the 1-SGPR-per-VALU rule + pk-pair packing). v8 (LDS coeffs, 16
// waves/CU) removed the mov source but lost TLP: ~34.6us. v4 (LDS
// coeffs, 32 waves/CU) spilled: full q-unroll hoists ~90 coeff VGPRs
// past the 64-reg cap. v9 = LDS coeffs + 32 waves/CU + hoist containment:
// __builtin_amdgcn_sched_barrier(0x7) after each q iteration (ALU may
// cross; DS/VMEM pinned) bounds live coeffs to ~1 iteration (~10 regs),
// est. total ~59 VGPR < 64. q-loop stays fully unrolled (runtime-indexed
// n[][] would go to scratch). 8 waves/SIMD TLP covers per-iter ds latency.
// Compute body = v5's verified math. Atomics combine channel partials.
__global__ __launch_bounds__(256, 8) void ka_conv_rational_kernel(
    const float* __restrict__ x,     // [B, C, H, W]
    const float* __restrict__ nums,  // [F*Q*C, 6]
    const float* __restrict__ dens,  // [F*Q*C, 4]
    float* __restrict__ out)         // [B, F, H, W]
{
    __shared__ float tile[2][TILE_N];    // 9248 B
    __shared__ float cf[CROWS * CROW_F]; // 2304 B  (11552 B total)

    const int t   = threadIdx.x;
    const int bid = blockIdx.x;          // 0..2047
    const int cs  = bid & (CSPLIT - 1);  // channel chunk
    const int bf  = bid >> 3;            // = b*NF + f, 0..255
    const int f   = bf & (NF - 1);
    const int bb  = bf >> 5;             // / NF
    const int xx  = t & 31;              // output column
    const int ty  = t >> 5;              // 0..7 -> owns rows 4*ty .. 4*ty+3
    const int c0  = cs * CPB;

    // c-invariant staging geometry: element idx of the 34x34 padded tile.
    int  soff[5];
    bool svalid[5];
#pragma unroll
    for (int i = 0; i < 5; ++i) {
        int idx = t + i * 256;
        int ry  = idx / TS;
        int rx  = idx - ry * TS;
        int gy  = ry - 1;
        int gx  = rx - 1;
        bool ok = (idx < TILE_N) && (gy >= 0) && (gy < NH) && (gx >= 0) && (gx < NW);
        svalid[i] = ok;
        soff[i]   = ok ? (gy * NW + gx) : 0; // clamped: always in-bounds
    }

    const float* __restrict__ xb = x + ((size_t)bb * NC + c0) * NH * NW;

    // ---- one-time coefficient staging into LDS (v4/v8's verified
    // pattern, CROWS=36). Covered by the first per-channel barrier. ----
    if (t < CROWS) {
        const int q = t >> 2, ci = t & (CPB - 1);
        const size_t r = ((size_t)(f * NQ + q)) * NC + (c0 + ci);
        const float* ap = nums + r * 6;      // 24 B, 8-B aligned
        f2 a01 = *(const f2*)ap;
        f2 a23 = *(const f2*)(ap + 2);
        f2 a45 = *(const f2*)(ap + 4);
        float* dst = cf + t * CROW_F;
        *(f2*)(dst)     = a01;
        *(f2*)(dst + 2) = a23;
        *(f2*)(dst + 4) = a45;
    } else if (t >= 128 && t < 128 + CROWS) {
        const int i = t - 128;
        const int q = i >> 2, ci = i & (CPB - 1);
        const size_t r = ((size_t)(f * NQ + q)) * NC + (c0 + ci);
        float4 dd = *(const float4*)(dens + r * 4); // 16 B aligned
        *(float4*)(cf + i * CROW_F + 8) = dd;
    }

    // prefetch first channel into registers
    float st[5];
#pragma unroll
    for (int i = 0; i < 5; ++i)
        st[i] = xb[soff[i]];

    f2 acc01 = {0.f, 0.f};
    f2 acc23 = {0.f, 0.f};

    for (int ci = 0; ci < CPB; ++ci) {
        float* tl = tile[ci & 1];

        // write staged channel (zero-padded) to LDS
#pragma unroll
        for (int i = 0; i < 5; ++i) {
            int idx = t + i * 256;
            if (idx < TILE_N) // i<4 always true; i=4: t<132
                tl[idx] = svalid[i] ? st[i] : 0.f;
        }
        // prefetch next channel (latency hidden behind compute below)
        if (ci + 1 < CPB) {
            const float* xc = xb + (size_t)(ci + 1) * NH * NW;
#pragma unroll
            for (int i = 0; i < 5; ++i)
                st[i] = xc[soff[i]];
        }
        __syncthreads(); // double-buffered: buffer (ci&1) next rewritten at ci+2

        // 6x3 neighborhood covering all 4 pixels' 3x3 windows
        float n[6][3];
#pragma unroll
        for (int dy = 0; dy < 6; ++dy)
#pragma unroll
            for (int dx = 0; dx < 3; ++dx)
                n[dy][dx] = tl[(ty * 4 + dy) * TS + (xx + dx)];

#pragma unroll
        for (int q = 0; q < NQ; ++q) {
            // coeff row from LDS: broadcast ds_read (b128+b64+b128),
            // base = ci*64 B (runtime), immediate offset q*256 B.
            const float* cp = cf + (q * CPB + ci) * CROW_F;
            float4 A03 = *(const float4*)cp;        // a0 a1 a2 a3
            f2     A45 = *(const f2*)(cp + 4);      // a4 a5
            float4 DD  = *(const float4*)(cp + 8);  // d0 d1 d2 d3
            const int qi = q / 3, qj = q - qi * 3;

            // 4 pixels' terms as two <2 x float> streams (v_pk_* ops)
            f2 w01 = {n[qi][qj],     n[qi + 1][qj]};
            f2 w23 = {n[qi + 2][qj], n[qi + 3][qj]};

            f2 nu01 = __builtin_elementwise_fma(sp(A45.y), w01, sp(A45.x));
            f2 nu23 = __builtin_elementwise_fma(sp(A45.y), w23, sp(A45.x));
            nu01 = __builtin_elementwise_fma(nu01, w01, sp(A03.w));
            nu23 = __builtin_elementwise_fma(nu23, w23, sp(A03.w));
            nu01 = __builtin_elementwise_fma(nu01, w01, sp(A03.z));
            nu23 = __builtin_elementwise_fma(nu23, w23, sp(A03.z));
            nu01 = __builtin_elementwise_fma(nu01, w01, sp(A03.y));
            nu23 = __builtin_elementwise_fma(nu23, w23, sp(A03.y));
            nu01 = __builtin_elementwise_fma(nu01, w01, sp(A03.x));
            nu23 = __builtin_elementwise_fma(nu23, w23, sp(A03.x));

            f2 dp01 = __builtin_elementwise_fma(sp(DD.w), w01, sp(DD.z));
            f2 dp23 = __builtin_elementwise_fma(sp(DD.w), w23, sp(DD.z));
            dp01 = __builtin_elementwise_fma(dp01, w01, sp(DD.y));
            dp23 = __builtin_elementwise_fma(dp23, w23, sp(DD.y));
            dp01 = __builtin_elementwise_fma(dp01, w01, sp(DD.x));
            dp23 = __builtin_elementwise_fma(dp23, w23, sp(DD.x));
            dp01 = dp01 * w01;
            dp23 = dp23 * w23;

            f2 de01 = 1.0f + __builtin_elementwise_abs(dp01);
            f2 de23 = 1.0f + __builtin_elementwise_abs(dp23);
            f2 r01 = {__builtin_amdgcn_rcpf(de01.x), __builtin_amdgcn_rcpf(de01.y)};
            f2 r23 = {__builtin_amdgcn_rcpf(de23.x), __builtin_amdgcn_rcpf(de23.y)};
            acc01 = __builtin_elementwise_fma(nu01, r01, acc01);
            acc23 = __builtin_elementwise_fma(nu23, r23, acc23);

            // Hoist fence: DS/VMEM may not cross (keeps next q's coeff
            // ds_reads in their own iteration -> ~10 live coeff VGPRs,
            // not 90); ALU/VALU/SALU free to schedule across.
            __builtin_amdgcn_sched_barrier(0x7);
        }
    }

    const int y0 = ty * 4;
    float* op = out + ((size_t)bf * NH + y0) * NW + xx;
    unsafeAtomicAdd(op,          acc01.x);
    unsafeAtomicAdd(op + NW,     acc01.y);
    unsafeAtomicAdd(op + 2 * NW, acc23.x);
    unsafeAtomicAdd(op + 3 * NW, acc23.y);
}

extern "C" void kernel_launch(void* const* d_in, const int* in_sizes, int n_in,
                              void* d_out, int out_size, void* d_ws, size_t ws_size,
                              hipStream_t stream) {
    const float* x    = (const float*)d_in[0];
    const float* nums = (const float*)d_in[1];
    const float* dens = (const float*)d_in[2];
    float* out = (float*)d_out;

    // atomic accumulation target must start at zero (harness poisons d_out)
    hipMemsetAsync(d_out, 0, (size_t)out_size * sizeof(float), stream);

    dim3 grid(NB * NF * CSPLIT); // 2048 blocks: (b, f, csplit) -> 8/CU
    dim3 block(256);
    ka_conv_rational_kernel<<<grid, block, 0, stream>>>(x, nums, dens, out);
}

// Round 12
// 85.661 us; speedup vs baseline: 6.9392x; 6.9392x over previous
//
#include <hip/hip_runtime.h>
#include <math.h>

// Problem constants (from reference): B=8, C=32, F=32, K=3, H=W=32
#define NB 8
#define NC 32
#define NF 32
#define NH 32
#define NW 32
#define NQ 9
#define FSPLIT 8   // f-quads per (b,y)
#define FPB 4      // f per block = ONE PER WAVE

// v10: CHANNELS ON LANES. All session evidence says the kernel is
// VALU-issue-bound (v7: VALUBusy 64% => v5 ~95%) with ~2x instruction
// fat from wave-uniform coefficient handling; every wave-uniform feed
// is now measured-dead: s_load 31.5us (SGPR movs + lgkm waits), VMEM
// 70us (addr flood), LDS spills at 64-VGPR cap (v4/v9) or loses
// occupancy at 128 (v8: 34.6us). Flip the mapping instead:
//   lane = channel c (both 32-lane halves; half = pixel-slot parity),
//   wave = one f, block = 4 f x one output row y, grid = 8b*32y*8fq
//   = 2048 blocks = 8/CU (13KB LDS, <=64 VGPR) in ONE resident round.
// Consequences:
//  - coeff loads are per-lane VMEM on the CONTIGUOUS c-axis: 32 lanes
//    span 768B/512B contiguous (12/8 lines, 100% used, L2-hot 368KB
//    table), land in VGPRs (no SGPR rule, no splat movs), rolling
//    q-prefetch hides latency under 192 VALU ops.
//  - eval is scalar Horner, 12 VALU/eval, zero marshalling.
//  - c-sum = 5-step __shfl_xor butterfly per half-wave -> NO atomics,
//    NO out-memset: each output stored exactly once, directly.
//  - x tile [32c][3][34] LDS: w-reads stride 408B = 16 banks x 2 lanes
//    + odd-offset upper half -> conflict-free.
__global__ __launch_bounds__(256, 8) void ka_conv_rational_kernel(
    const float* __restrict__ x,     // [B, C, H, W]
    const float* __restrict__ nums,  // [F*Q*C, 6]
    const float* __restrict__ dens,  // [F*Q*C, 4]
    float* __restrict__ out)         // [B, F, H, W]
{
    __shared__ float xt[NC][3][NW + 2]; // 13,056 B

    const int t   = threadIdx.x;
    const int bid = blockIdx.x;        // 0..2047 = (b, y, fq)
    const int fq  = bid & (FSPLIT - 1);
    const int y   = (bid >> 3) & (NH - 1);
    const int b   = bid >> 8;

    // ---- stage x[b, all c, y-1..y+1, all cols] zero-padded (coalesced:
    // consecutive threads -> consecutive cols of 128B rows) ----
#pragma unroll
    for (int i = 0; i < 12; ++i) {
        int e   = t + i * 256;           // 12*256 = 3072 = 32c*3r*32col
        int c   = e >> 5;                // e / 32: (c,ri) packed
        int ri  = c - (c / 3) * 3;       // careful: decode as below instead
        (void)ri;
        int cc  = e / 96;                // channel
        int rem = e - cc * 96;
        int rr  = rem >> 5;              // row 0..2
        int col = rem & 31;
        int gy  = y - 1 + rr;
        float v = (gy >= 0 && gy < NH)
                      ? x[(((size_t)b * NC + cc) * NH + gy) * NW + col]
                      : 0.f;
        xt[cc][rr][col + 1] = v;
    }
    // pad columns 0 and 33
    if (t < 96) {
        int cc = t / 3, rr = t - (t / 3) * 3;
        xt[cc][rr][0] = 0.f;
    } else if (t >= 128 && t < 224) {
        int u = t - 128;
        int cc = u / 3, rr = u - (u / 3) * 3;
        xt[cc][rr][33] = 0.f;
    }
    __syncthreads(); // only barrier

    const int lane = t & 63;
    const int c    = lane & 31; // this lane's channel
    const int sl   = lane >> 5; // pixel-slot parity (px = 2*it + sl)
    const int wv   = t >> 6;    // 0..3
    const int f    = fq * FPB + wv;

    const float* __restrict__ nbase = nums + ((size_t)f * NQ * NC + c) * 6;
    const float* __restrict__ dbase = dens + ((size_t)f * NQ * NC + c) * 4;

    float acc[16];
#pragma unroll
    for (int i = 0; i < 16; ++i) acc[i] = 0.f;

    // prefetch q=0 coefficients (per-lane, coalesced over c)
    float A0 = nbase[0], A1 = nbase[1], A2 = nbase[2],
          A3 = nbase[3], A4 = nbase[4], A5 = nbase[5];
    float D0 = dbase[0], D1 = dbase[1], D2 = dbase[2], D3 = dbase[3];

#pragma unroll 1
    for (int q = 0; q < NQ; ++q) {
        const float a0 = A0, a1 = A1, a2 = A2, a3 = A3, a4 = A4, a5 = A5;
        const float d0 = D0, d1 = D1, d2 = D2, d3 = D3;
        if (q + 1 < NQ) { // rolling prefetch of next q's coefficients
            const float* nn = nbase + (size_t)(q + 1) * NC * 6;
            const float* dn = dbase + (size_t)(q + 1) * NC * 4;
            A0 = nn[0]; A1 = nn[1]; A2 = nn[2];
            A3 = nn[3]; A4 = nn[4]; A5 = nn[5];
            D0 = dn[0]; D1 = dn[1]; D2 = dn[2]; D3 = dn[3];
        }
        const int qi = q / 3, qj = q - qi * 3; // uniform (SALU)
        const float* wrow = &xt[c][qi][qj + sl];

#pragma unroll
        for (int it = 0; it < 16; ++it) {
            float w  = wrow[it * 2]; // w = x[b,c,y+qi-1, (2*it+sl)+qj-1]
            float nu = fmaf(a5, w, a4);
            nu = fmaf(nu, w, a3);
            nu = fmaf(nu, w, a2);
            nu = fmaf(nu, w, a1);
            nu = fmaf(nu, w, a0);
            float dd = fmaf(d3, w, d2);
            dd = fmaf(dd, w, d1);
            dd = fmaf(dd, w, d0);
            dd *= w;
            float de = 1.0f + fabsf(dd);
            acc[it] = fmaf(nu, __builtin_amdgcn_rcpf(de), acc[it]);
        }
    }

    // ---- c-sum: 5-step butterfly within each 32-lane half ----
#pragma unroll
    for (int it = 0; it < 16; ++it) {
        float v = acc[it];
        v += __shfl_xor(v, 1, 64);
        v += __shfl_xor(v, 2, 64);
        v += __shfl_xor(v, 4, 64);
        v += __shfl_xor(v, 8, 64);
        v += __shfl_xor(v, 16, 64);
        acc[it] = v;
    }

    // lane with c==it stores pixel px = 2*it + sl (each output exactly once)
    float* op = out + (((size_t)b * NF + f) * NH + y) * NW;
#pragma unroll
    for (int it = 0; it < 16; ++it)
        if (c == it)
            op[it * 2 + sl] = acc[it];
}

extern "C" void kernel_launch(void* const* d_in, const int* in_sizes, int n_in,
                              void* d_out, int out_size, void* d_ws, size_t ws_size,
                              hipStream_t stream) {
    const float* x    = (const float*)d_in[0];
    const float* nums = (const float*)d_in[1];
    const float* dens = (const float*)d_in[2];
    float* out = (float*)d_out;

    // no memset needed: every output element is written by exactly one
    // direct store (no atomic accumulation in this structure).
    dim3 grid(NB * NH * FSPLIT); // 2048 blocks: (b, y, f-quad) -> 8/CU
    dim3 block(256);
    ka_conv_rational_kernel<<<grid, block, 0, stream>>>(x, nums, dens, out);
}